// Round 10
// baseline (285.523 us; speedup 1.0000x reference)
//
#include <hip/hip_runtime.h>
#include <hip/hip_bf16.h>

typedef __attribute__((ext_vector_type(8))) short short8;
typedef __attribute__((ext_vector_type(4))) float floatx4;
typedef __attribute__((ext_vector_type(4))) unsigned short ushort4v;
typedef __attribute__((ext_vector_type(8))) unsigned short ushort8v;
typedef __attribute__((ext_vector_type(2))) unsigned int uint2v;
typedef __attribute__((ext_vector_type(4))) unsigned int uint4v;

#define NN 10000
#define E0 160000
#define ETOT (E0 + NN)
#define IN_DIM 512
#define HID1 1024   /* HEADS*HID = 8*128 */
#define EMB 256
#define MPAD 10112  /* 79 * 128 */
#define NX (NN * IN_DIM)
#define NW1 (IN_DIM * HID1)
#define NW2 (HID1 * EMB)

__device__ __forceinline__ float bf2f(unsigned short u) {
    unsigned v = ((unsigned)u) << 16;
    float f;
    __builtin_memcpy(&f, &v, 4);
    return f;
}
__device__ __forceinline__ float bflo(unsigned v) {
    unsigned x = v << 16;
    float f; __builtin_memcpy(&f, &x, 4);
    return f;
}
__device__ __forceinline__ float bfhi(unsigned v) {
    unsigned x = v & 0xffff0000u;
    float f; __builtin_memcpy(&f, &x, 4);
    return f;
}
__device__ __forceinline__ unsigned short f2bf(float f) {
    unsigned u;
    __builtin_memcpy(&u, &f, 4);
    unsigned lsb = (u >> 16) & 1;
    u += 0x7fff + lsb;           // round-to-nearest-even
    return (unsigned short)(u >> 16);
}
__device__ __forceinline__ float loadf(const void* p, size_t i, int isf32) {
    if (isf32) return ((const float*)p)[i];
    return bf2f(((const unsigned short*)p)[i]);
}
__device__ __forceinline__ float lrelu(float e) { return e > 0.f ? e : 0.2f * e; }

// ---------------- fused zero + dtype probes ----------------
// Zero span now also covers h2f (split-K accumulator).
__global__ __launch_bounds__(256) void probezero_kernel(
    const int* __restrict__ ei32, const unsigned* __restrict__ xw,
    int* __restrict__ zbase, int zn, int* __restrict__ eflag, int* __restrict__ isf32)
{
    int b = blockIdx.x, t = threadIdx.x;
    int i = b * 256 + t;
    if (i < zn) zbase[i] = 0;
    if (b == 0) {
        int any = 0;
        #pragma unroll
        for (int k = 0; k < 64; ++k) {
            int idx = (t + k * 256) * 2 + 1;   // < 32768*2 < 2*E0
            any |= ei32[idx];
        }
        __shared__ int sf;
        if (t == 0) sf = 0;
        __syncthreads();
        if (any) atomicOr(&sf, 1);
        __syncthreads();
        if (t == 0) *eflag = sf;
    } else if (b == 1) {
        __shared__ int cnt[256];
        int c = 0;
        #pragma unroll
        for (int j = 0; j < 16; ++j) {
            unsigned w = xw[t * 16 + j];
            int ex = (w >> 7) & 0xFF;
            if (ex >= 110 && ex <= 135) c++;
        }
        cnt[t] = c;
        __syncthreads();
        for (int off = 128; off > 0; off >>= 1) {
            if (t < off) cnt[t] += cnt[t + off];
            __syncthreads();
        }
        if (t == 0) *isf32 = (cnt[0] < 2048) ? 1 : 0;
    }
}

__device__ __forceinline__ int load_edge(const void* ei, long long idx, int m32) {
    if (m32) return ((const int*)ei)[idx];
    return (int)(((const long long*)ei)[idx]);
}

// ---------------- CSR build ----------------
__global__ void count_kernel(const void* ei, const int* flag, int* counts) {
    int e = blockIdx.x * 256 + threadIdx.x;
    if (e < E0) {
        int m32 = (*flag != 0);
        int d = load_edge(ei, (long long)E0 + e, m32);
        if (d >= 0 && d < NN) atomicAdd(&counts[d], 1);
    }
}

// shfl-based block scan: 1024 threads x 10 values, 2 barriers total.
__global__ __launch_bounds__(1024) void scan_kernel(const int* counts, int* offsets, int* cursor) {
    __shared__ int wsum[16];
    int t = threadIdx.x;
    int lane = t & 63, wv = t >> 6;
    int base = t * 10;
    int local[10];
    int s = 0;
    #pragma unroll
    for (int j = 0; j < 10; ++j) {
        int idx = base + j;
        int v = (idx < NN) ? (counts[idx] + 1) : 0;  // +1 self loop
        local[j] = v; s += v;
    }
    int v = s;
    #pragma unroll
    for (int d = 1; d < 64; d <<= 1) {
        int o = __shfl_up(v, d, 64);
        if (lane >= d) v += o;
    }
    if (lane == 63) wsum[wv] = v;
    __syncthreads();
    if (t < 16) {
        int w = wsum[t];
        #pragma unroll
        for (int d = 1; d < 16; d <<= 1) {
            int o = __shfl_up(w, d, 16);
            if (t >= d) w += o;
        }
        wsum[t] = w;
    }
    __syncthreads();
    int woff = (wv == 0) ? 0 : wsum[wv - 1];
    int run = woff + v - s;
    #pragma unroll
    for (int j = 0; j < 10; ++j) {
        int idx = base + j;
        if (idx < NN) { offsets[idx] = run; cursor[idx] = run; run += local[j]; }
    }
    if (t == 1023) offsets[NN] = wsum[15];
}

__global__ void scatter_kernel(const void* ei, const int* flag, int* cursor, int* csr_src) {
    int e = blockIdx.x * 256 + threadIdx.x;
    if (e >= ETOT) return;
    int m32 = (*flag != 0);
    int s, d;
    if (e < E0) { s = load_edge(ei, e, m32); d = load_edge(ei, (long long)E0 + e, m32); }
    else { s = d = e - E0; }
    if (s < 0) s = 0; if (s >= NN) s = NN - 1;
    if (d < 0) d = 0; if (d >= NN) d = NN - 1;
    int pos = atomicAdd(&cursor[d], 1);
    if (pos >= 0 && pos < ETOT) csr_src[pos] = s;
}

// ---------------- fused fp32->bf16 conversions (x, W1^T, W2^T in one launch) ----------------
__global__ void convall_kernel(const void* x, const void* W1, const void* W2,
                               unsigned short* xb, unsigned short* W1t, unsigned short* W2t,
                               const int* isf32)
{
    int i = blockIdx.x * 256 + threadIdx.x;
    int f = *isf32;
    if (i < NX) { xb[i] = f2bf(loadf(x, i, f)); return; }
    i -= NX;
    if (i < NW1) {
        int r = i / HID1, c = i % HID1;
        W1t[(size_t)c * IN_DIM + r] = f2bf(loadf(W1, i, f));
        return;
    }
    i -= NW1;
    if (i < NW2) {
        int r = i / EMB, c = i % EMB;
        W2t[(size_t)c * HID1 + r] = f2bf(loadf(W2, i, f));
    }
}

// ---------------- m97-style MFMA GEMM with fused alpha epilogue ----------------
// SPLITK=false: bf16 C store, K-range [0,K). SPLITK=true: f32 atomicAdd C accumulation,
// K-range [kbeg,kend) — grid.z slices; alpha epilogue partials are linear in C so the
// per-slice atomics sum correctly.
template<int HSHIFT, int HN, bool SPLITK>
__global__ __launch_bounds__(256) void gemm_tile(
    const unsigned short* __restrict__ A,
    const unsigned short* __restrict__ Bt,
    void* __restrict__ Cv, int N, int K, int kslice,
    const void* __restrict__ a_src, const void* __restrict__ a_dst,
    const int* __restrict__ isf32,
    float* __restrict__ as_out, float* __restrict__ ad_out)
{
    __shared__ unsigned short As[128 * 32];
    __shared__ unsigned short Bs[128 * 32];
    int t = threadIdx.x;
    int wave = t >> 6;
    int lane = t & 63;
    int quad = lane >> 4;
    int l16  = lane & 15;
    int mq = wave & 1, nq = wave >> 1;
    size_t mblk = (size_t)blockIdx.x * 128;
    size_t nblk = (size_t)blockIdx.y * 128;
    int kbeg = SPLITK ? blockIdx.z * kslice : 0;
    int kend = SPLITK ? kbeg + kslice : K;

    floatx4 acc[4][4];
    #pragma unroll
    for (int i = 0; i < 4; ++i)
        #pragma unroll
        for (int j = 0; j < 4; ++j)
            acc[i][j] = (floatx4){0.f, 0.f, 0.f, 0.f};

    const unsigned short* Abase = A + mblk * K;
    const unsigned short* Bbase = Bt + nblk * K;

    for (int kk = kbeg; kk < kend; kk += 32) {
        __syncthreads();
        #pragma unroll
        for (int j = 0; j < 2; ++j) {
            int chunk = (wave << 7) + (j << 6) + lane;
            int r  = chunk >> 2;
            int cs = (chunk & 3) ^ (r & 3);
            const unsigned short* ga = Abase + (size_t)r * K + kk + cs * 8;
            const unsigned short* gb = Bbase + (size_t)r * K + kk + cs * 8;
            __builtin_amdgcn_global_load_lds(
                (const __attribute__((address_space(1))) void*)ga,
                (__attribute__((address_space(3))) void*)(As + (size_t)((wave << 7) + (j << 6)) * 8),
                16, 0, 0);
            __builtin_amdgcn_global_load_lds(
                (const __attribute__((address_space(1))) void*)gb,
                (__attribute__((address_space(3))) void*)(Bs + (size_t)((wave << 7) + (j << 6)) * 8),
                16, 0, 0);
        }
        __syncthreads();

        short8 af[4], bf[4];
        #pragma unroll
        for (int i = 0; i < 4; ++i) {
            int ar = mq * 64 + i * 16 + l16;
            int br = nq * 64 + i * 16 + l16;
            af[i] = *(const short8*)(const void*)(As + ar * 32 + (quad ^ (ar & 3)) * 8);
            bf[i] = *(const short8*)(const void*)(Bs + br * 32 + (quad ^ (br & 3)) * 8);
        }
        #pragma unroll
        for (int i = 0; i < 4; ++i)
            #pragma unroll
            for (int j = 0; j < 4; ++j)
                acc[i][j] = __builtin_amdgcn_mfma_f32_16x16x32_bf16(af[i], bf[j], acc[i][j], 0, 0, 0);
    }

    size_t crow0 = mblk + mq * 64 + quad * 4;
    size_t ccol0 = nblk + nq * 64 + l16;
    #pragma unroll
    for (int i = 0; i < 4; ++i) {
        #pragma unroll
        for (int r = 0; r < 4; ++r) {
            size_t row = crow0 + i * 16 + r;
            size_t b = row * N + ccol0;
            #pragma unroll
            for (int j = 0; j < 4; ++j) {
                if (SPLITK) atomicAdd(&((float*)Cv)[b + j * 16], acc[i][j][r]);
                else        ((unsigned short*)Cv)[b + j * 16] = f2bf(acc[i][j][r]);
            }
        }
    }

    // fused alpha partials (pre-rounding f32 acc; per-slice partials sum via atomics)
    int f = *isf32;
    float a_s[4], a_d[4];
    #pragma unroll
    for (int j = 0; j < 4; ++j) {
        a_s[j] = loadf(a_src, ccol0 + j * 16, f);
        a_d[j] = loadf(a_dst, ccol0 + j * 16, f);
    }
    int head = (int)((nblk + (size_t)nq * 64) >> HSHIFT);
    #pragma unroll
    for (int i = 0; i < 4; ++i) {
        #pragma unroll
        for (int r = 0; r < 4; ++r) {
            float ps = acc[i][0][r] * a_s[0] + acc[i][1][r] * a_s[1]
                     + acc[i][2][r] * a_s[2] + acc[i][3][r] * a_s[3];
            float pd = acc[i][0][r] * a_d[0] + acc[i][1][r] * a_d[1]
                     + acc[i][2][r] * a_d[2] + acc[i][3][r] * a_d[3];
            #pragma unroll
            for (int off = 1; off < 16; off <<= 1) {
                ps += __shfl_xor(ps, off, 16);
                pd += __shfl_xor(pd, off, 16);
            }
            if (l16 == 0) {
                size_t row = crow0 + i * 16 + r;
                if (row < NN) {
                    atomicAdd(&as_out[row * HN + head], ps);
                    atomicAdd(&ad_out[row * HN + head], pd);
                }
            }
        }
    }
}

// ---------------- layer-1 single-pass softmax-aggregate + ELU -> hmid bf16 ----------------
// R3/R8 proven 49.5us structure (fabric-bound beats both partitioned 59us variants).
__global__ __launch_bounds__(256) void agg1_kernel(
    const unsigned short* __restrict__ h1, const int* __restrict__ offsets,
    const int* __restrict__ csr_src, const float* __restrict__ as1,
    const float* __restrict__ ad1, const void* __restrict__ b1,
    const int* __restrict__ isf32,
    unsigned short* __restrict__ hmid)
{
    int n = blockIdx.x, t = threadIdx.x;
    int f = *isf32;
    int beg = offsets[n], end = offsets[n + 1];
    if (beg < 0) beg = 0; if (end > ETOT) end = ETOT;
    int g = t >> 7;          // edge group 0/1
    int u = t & 127;
    int c0 = u * 8;          // 8 cols per thread
    int hc = u >> 4;         // head = c0/128
    float ad = ad1[n * 8 + hc];

    float den = 0.f;
    float acc[8];
    #pragma unroll
    for (int j = 0; j < 8; ++j) acc[j] = 0.f;

    int i = beg + g;
    for (; i + 6 < end; i += 8) {
        int s0 = csr_src[i];     s0 &= 0x7fffffff; if (s0 >= NN) s0 = 0;
        int s1 = csr_src[i + 2]; s1 &= 0x7fffffff; if (s1 >= NN) s1 = 0;
        int s2 = csr_src[i + 4]; s2 &= 0x7fffffff; if (s2 >= NN) s2 = 0;
        int s3 = csr_src[i + 6]; s3 &= 0x7fffffff; if (s3 >= NN) s3 = 0;
        ushort8v hv0 = *(const ushort8v*)(const void*)(h1 + (size_t)s0 * HID1 + c0);
        ushort8v hv1 = *(const ushort8v*)(const void*)(h1 + (size_t)s1 * HID1 + c0);
        ushort8v hv2 = *(const ushort8v*)(const void*)(h1 + (size_t)s2 * HID1 + c0);
        ushort8v hv3 = *(const ushort8v*)(const void*)(h1 + (size_t)s3 * HID1 + c0);
        float e0 = as1[s0 * 8 + hc] + ad;
        float e1 = as1[s1 * 8 + hc] + ad;
        float e2 = as1[s2 * 8 + hc] + ad;
        float e3 = as1[s3 * 8 + hc] + ad;
        e0 = e0 > 0.f ? e0 : 0.2f * e0;
        e1 = e1 > 0.f ? e1 : 0.2f * e1;
        e2 = e2 > 0.f ? e2 : 0.2f * e2;
        e3 = e3 > 0.f ? e3 : 0.2f * e3;
        float w0 = __expf(e0), w1 = __expf(e1), w2 = __expf(e2), w3 = __expf(e3);
        den += (w0 + w1) + (w2 + w3);
        #pragma unroll
        for (int j = 0; j < 8; ++j)
            acc[j] += (bf2f(hv0[j]) * w0 + bf2f(hv1[j]) * w1)
                    + (bf2f(hv2[j]) * w2 + bf2f(hv3[j]) * w3);
    }
    for (; i + 2 < end; i += 4) {
        int s0 = csr_src[i];     s0 &= 0x7fffffff; if (s0 >= NN) s0 = 0;
        int s1 = csr_src[i + 2]; s1 &= 0x7fffffff; if (s1 >= NN) s1 = 0;
        ushort8v hv0 = *(const ushort8v*)(const void*)(h1 + (size_t)s0 * HID1 + c0);
        ushort8v hv1 = *(const ushort8v*)(const void*)(h1 + (size_t)s1 * HID1 + c0);
        float e0 = as1[s0 * 8 + hc] + ad;
        float e1 = as1[s1 * 8 + hc] + ad;
        e0 = e0 > 0.f ? e0 : 0.2f * e0;
        e1 = e1 > 0.f ? e1 : 0.2f * e1;
        float w0 = __expf(e0), w1 = __expf(e1);
        den += w0 + w1;
        #pragma unroll
        for (int j = 0; j < 8; ++j)
            acc[j] += bf2f(hv0[j]) * w0 + bf2f(hv1[j]) * w1;
    }
    if (i < end) {
        int s0 = csr_src[i]; s0 &= 0x7fffffff; if (s0 >= NN) s0 = 0;
        ushort8v hv0 = *(const ushort8v*)(const void*)(h1 + (size_t)s0 * HID1 + c0);
        float e0 = as1[s0 * 8 + hc] + ad;
        e0 = e0 > 0.f ? e0 : 0.2f * e0;
        float w0 = __expf(e0);
        den += w0;
        #pragma unroll
        for (int j = 0; j < 8; ++j) acc[j] += bf2f(hv0[j]) * w0;
    }

    __shared__ float accsh[128][9];
    __shared__ float densh[128];
    if (g == 1) {
        #pragma unroll
        for (int j = 0; j < 8; ++j) accsh[u][j] = acc[j];
        densh[u] = den;
    }
    __syncthreads();
    if (g == 0) {
        den += densh[u];
        float rden = 1.0f / fmaxf(den, 1e-30f);
        ushort8v outw;
        #pragma unroll
        for (int j = 0; j < 8; ++j) {
            float v = (acc[j] + accsh[u][j]) * rden + loadf(b1, c0 + j, f);
            v = v > 0.f ? v : (__expf(v) - 1.0f);   // ELU
            outw[j] = f2bf(v);
        }
        *(ushort8v*)(void*)(hmid + (size_t)n * HID1 + c0) = outw;
    }
}

// ---------------- layer-2 softmax-aggregate, COLUMN-CHUNK-PARTITIONED, f32 rows ----------------
// Reads split-K accumulator h2f directly (f32): no unpack ops; chunk slice = 2.56MB/XCD, L2-fits.
__global__ __launch_bounds__(256) void agg2_kernel(
    const float* __restrict__ h2, const int* __restrict__ offsets,
    const int* __restrict__ csr_src, const float* __restrict__ as2,
    const float* __restrict__ ad2, const void* __restrict__ b2,
    const int* __restrict__ isf32,
    float* __restrict__ out)
{
    int chunk = blockIdx.x & 3;
    int ng    = blockIdx.x >> 2;
    int n     = ng * 4 + (threadIdx.x >> 6);
    if (n >= NN) return;
    int lane = threadIdx.x & 63;
    int q    = lane >> 4;      // edge quarter-group 0..3
    int sl   = lane & 15;      // 4 cols: chunk*64 + sl*4 ..
    int f = *isf32;
    int beg = offsets[n], end = offsets[n + 1];
    if (beg < 0) beg = 0; if (end > ETOT) end = ETOT;
    float adn = ad2[n];
    const float* rb = h2 + chunk * 64 + sl * 4;   // + s*256

    float den = 0.f;
    float acc[4];
    #pragma unroll
    for (int j = 0; j < 4; ++j) acc[j] = 0.f;

    int i = beg + q;
    for (; i + 12 < end; i += 16) {
        int s0 = csr_src[i];      s0 &= 0x7fffffff; if (s0 >= NN) s0 = 0;
        int s1 = csr_src[i + 4];  s1 &= 0x7fffffff; if (s1 >= NN) s1 = 0;
        int s2 = csr_src[i + 8];  s2 &= 0x7fffffff; if (s2 >= NN) s2 = 0;
        int s3 = csr_src[i + 12]; s3 &= 0x7fffffff; if (s3 >= NN) s3 = 0;
        floatx4 v0 = *(const floatx4*)(const void*)(rb + (size_t)s0 * 256);
        floatx4 v1 = *(const floatx4*)(const void*)(rb + (size_t)s1 * 256);
        floatx4 v2 = *(const floatx4*)(const void*)(rb + (size_t)s2 * 256);
        floatx4 v3 = *(const floatx4*)(const void*)(rb + (size_t)s3 * 256);
        float w0 = __expf(lrelu(as2[s0] + adn));
        float w1 = __expf(lrelu(as2[s1] + adn));
        float w2 = __expf(lrelu(as2[s2] + adn));
        float w3 = __expf(lrelu(as2[s3] + adn));
        den += (w0 + w1) + (w2 + w3);
        #pragma unroll
        for (int j = 0; j < 4; ++j)
            acc[j] += (v0[j] * w0 + v1[j] * w1) + (v2[j] * w2 + v3[j] * w3);
    }
    for (; i + 4 < end; i += 8) {
        int s0 = csr_src[i];     s0 &= 0x7fffffff; if (s0 >= NN) s0 = 0;
        int s1 = csr_src[i + 4]; s1 &= 0x7fffffff; if (s1 >= NN) s1 = 0;
        floatx4 v0 = *(const floatx4*)(const void*)(rb + (size_t)s0 * 256);
        floatx4 v1 = *(const floatx4*)(const void*)(rb + (size_t)s1 * 256);
        float w0 = __expf(lrelu(as2[s0] + adn));
        float w1 = __expf(lrelu(as2[s1] + adn));
        den += w0 + w1;
        #pragma unroll
        for (int j = 0; j < 4; ++j)
            acc[j] += v0[j] * w0 + v1[j] * w1;
    }
    if (i < end) {
        int s0 = csr_src[i]; s0 &= 0x7fffffff; if (s0 >= NN) s0 = 0;
        floatx4 v0 = *(const floatx4*)(const void*)(rb + (size_t)s0 * 256);
        float w0 = __expf(lrelu(as2[s0] + adn));
        den += w0;
        #pragma unroll
        for (int j = 0; j < 4; ++j) acc[j] += v0[j] * w0;
    }

    #pragma unroll
    for (int j = 0; j < 4; ++j) {
        acc[j] += __shfl_xor(acc[j], 16, 64);
        acc[j] += __shfl_xor(acc[j], 32, 64);
    }
    den += __shfl_xor(den, 16, 64);
    den += __shfl_xor(den, 32, 64);

    if (q == 0) {
        float rden = 1.0f / fmaxf(den, 1e-30f);
        int c0 = chunk * 64 + sl * 4;
        floatx4 o;
        #pragma unroll
        for (int j = 0; j < 4; ++j)
            o[j] = acc[j] * rden + loadf(b2, c0 + j, f);
        *(floatx4*)(void*)(out + (size_t)n * EMB + c0) = o;
    }
}

extern "C" void kernel_launch(void* const* d_in, const int* in_sizes, int n_in,
                              void* d_out, int out_size, void* d_ws, size_t ws_size,
                              hipStream_t stream)
{
    const void* x      = d_in[0];
    const void* edge   = d_in[1];
    const void* W1     = d_in[2];
    const void* a_src1 = d_in[3];
    const void* a_dst1 = d_in[4];
    const void* b1     = d_in[5];
    const void* W2     = d_in[6];
    const void* a_src2 = d_in[7];
    const void* a_dst2 = d_in[8];
    const void* b2     = d_in[9];
    float* out = (float*)d_out;

    char* ws = (char*)d_ws;
    size_t off = 0;
    auto alloc = [&](size_t bytes) -> void* {
        void* p = ws + off;
        off += (bytes + 255) & ~(size_t)255;
        return p;
    };
    // zero span: counts..h2f contiguous (zeroed by probezero_kernel)
    int*            counts = (int*)alloc((size_t)NN * 4);
    float*          as1    = (float*)alloc((size_t)NN * 8 * 4);
    float*          ad1    = (float*)alloc((size_t)NN * 8 * 4);
    float*          as2    = (float*)alloc((size_t)NN * 4);
    float*          ad2    = (float*)alloc((size_t)NN * 4);
    float*          h2f    = (float*)alloc((size_t)MPAD * EMB * 4);   // split-K accumulator
    int             zn     = (int)(((char*)h2f - (char*)counts) / 4) + MPAD * EMB;
    int*            flags  = (int*)alloc(2 * 4);          // [0]=eflag [1]=isf32 (NOT zeroed)
    int*            offs   = (int*)alloc((NN + 1) * 4);
    int*            cursor = (int*)alloc(NN * 4);
    int*            csr    = (int*)alloc((size_t)ETOT * 4);
    unsigned short* xb     = (unsigned short*)alloc((size_t)MPAD * IN_DIM * 2);
    unsigned short* W1t    = (unsigned short*)alloc((size_t)IN_DIM * HID1 * 2);
    unsigned short* W2t    = (unsigned short*)alloc((size_t)HID1 * EMB * 2);
    unsigned short* h1b    = (unsigned short*)alloc((size_t)MPAD * HID1 * 2);
    unsigned short* hmid   = (unsigned short*)alloc((size_t)MPAD * HID1 * 2);
    int* eflag = flags;
    int* isf32 = flags + 1;

    probezero_kernel<<<(zn + 255) / 256, 256, 0, stream>>>(
        (const int*)edge, (const unsigned*)x, counts, zn, eflag, isf32);

    count_kernel<<<(E0 + 255) / 256, 256, 0, stream>>>(edge, eflag, counts);
    scan_kernel<<<1, 1024, 0, stream>>>(counts, offs, cursor);
    scatter_kernel<<<(ETOT + 255) / 256, 256, 0, stream>>>(edge, eflag, cursor, csr);

    convall_kernel<<<(NX + NW1 + NW2 + 255) / 256, 256, 0, stream>>>(
        x, W1, W2, xb, W1t, W2t, isf32);

    // layer 1 GEMM + fused alpha1: h1b = x @ W1 (bf16 out)
    dim3 g1(MPAD / 128, HID1 / 128);
    gemm_tile<7, 8, false><<<g1, 256, 0, stream>>>(xb, W1t, h1b, HID1, IN_DIM, 0,
                                                   a_src1, a_dst1, isf32, as1, ad1);

    agg1_kernel<<<NN, 256, 0, stream>>>(h1b, offs, csr, as1, ad1, b1, isf32, hmid);

    // layer 2 GEMM, split-K=4 (grid 79x2x4 = 632 blocks vs 158): h2f += hmid @ W2 (f32 atomic);
    // fused alpha2 partials per slice sum via atomics (linear in C).
    dim3 g2(MPAD / 128, EMB / 128, 4);
    gemm_tile<8, 1, true><<<g2, 256, 0, stream>>>(hmid, W2t, h2f, EMB, HID1, HID1 / 4,
                                                  a_src2, a_dst2, isf32, as2, ad2);

    // chunk-partitioned agg2 reads f32 h2f directly
    agg2_kernel<<<(NN / 4) * 4, 256, 0, stream>>>(h2f, offs, csr, as2, ad2, b2, isf32, out);
}

// Round 11
// 264.398 us; speedup vs baseline: 1.0799x; 1.0799x over previous
//
#include <hip/hip_runtime.h>
#include <hip/hip_bf16.h>

typedef __attribute__((ext_vector_type(8))) short short8;
typedef __attribute__((ext_vector_type(4))) float floatx4;
typedef __attribute__((ext_vector_type(4))) unsigned short ushort4v;
typedef __attribute__((ext_vector_type(8))) unsigned short ushort8v;
typedef __attribute__((ext_vector_type(2))) unsigned int uint2v;
typedef __attribute__((ext_vector_type(4))) unsigned int uint4v;

#define NN 10000
#define E0 160000
#define ETOT (E0 + NN)
#define IN_DIM 512
#define HID1 1024   /* HEADS*HID = 8*128 */
#define EMB 256
#define MPAD 10112  /* 79 * 128 */
#define NX (NN * IN_DIM)
#define NW1 (IN_DIM * HID1)
#define NW2 (HID1 * EMB)

__device__ __forceinline__ float bf2f(unsigned short u) {
    unsigned v = ((unsigned)u) << 16;
    float f;
    __builtin_memcpy(&f, &v, 4);
    return f;
}
__device__ __forceinline__ float bflo(unsigned v) {
    unsigned x = v << 16;
    float f; __builtin_memcpy(&f, &x, 4);
    return f;
}
__device__ __forceinline__ float bfhi(unsigned v) {
    unsigned x = v & 0xffff0000u;
    float f; __builtin_memcpy(&f, &x, 4);
    return f;
}
__device__ __forceinline__ unsigned short f2bf(float f) {
    unsigned u;
    __builtin_memcpy(&u, &f, 4);
    unsigned lsb = (u >> 16) & 1;
    u += 0x7fff + lsb;           // round-to-nearest-even
    return (unsigned short)(u >> 16);
}
__device__ __forceinline__ float loadf(const void* p, size_t i, int isf32) {
    if (isf32) return ((const float*)p)[i];
    return bf2f(((const unsigned short*)p)[i]);
}
__device__ __forceinline__ float lrelu(float e) { return e > 0.f ? e : 0.2f * e; }

// ---------------- fused zero + dtype probes ----------------
// blocks 0..zb-1 zero the [counts..ad2] span. Block 0 additionally does the edge-dtype
// probe (16K odd-word samples, deterministic single-block -> no init race on eflag);
// block 1 does the float-dtype probe. eflag/isf32 live OUTSIDE the zero span.
__global__ __launch_bounds__(256) void probezero_kernel(
    const int* __restrict__ ei32, const unsigned* __restrict__ xw,
    int* __restrict__ zbase, int zn, int* __restrict__ eflag, int* __restrict__ isf32)
{
    int b = blockIdx.x, t = threadIdx.x;
    int i = b * 256 + t;
    if (i < zn) zbase[i] = 0;
    if (b == 0) {
        // int64 edges: odd words are high halves of src ids -> all 0.
        // int32 edges: odd words are node ids -> nonzero w.h.p. (16384 samples).
        int any = 0;
        #pragma unroll
        for (int k = 0; k < 64; ++k) {
            int idx = (t + k * 256) * 2 + 1;   // < 32768*2 < 2*E0
            any |= ei32[idx];
        }
        __shared__ int sf;
        if (t == 0) sf = 0;
        __syncthreads();
        if (any) atomicOr(&sf, 1);
        __syncthreads();
        if (t == 0) *eflag = sf;
    } else if (b == 1) {
        __shared__ int cnt[256];
        int c = 0;
        #pragma unroll
        for (int j = 0; j < 16; ++j) {
            unsigned w = xw[t * 16 + j];
            int ex = (w >> 7) & 0xFF;
            if (ex >= 110 && ex <= 135) c++;
        }
        cnt[t] = c;
        __syncthreads();
        for (int off = 128; off > 0; off >>= 1) {
            if (t < off) cnt[t] += cnt[t + off];
            __syncthreads();
        }
        if (t == 0) *isf32 = (cnt[0] < 2048) ? 1 : 0;
    }
}

__device__ __forceinline__ int load_edge(const void* ei, long long idx, int m32) {
    if (m32) return ((const int*)ei)[idx];
    return (int)(((const long long*)ei)[idx]);
}

// ---------------- CSR build ----------------
__global__ void count_kernel(const void* ei, const int* flag, int* counts) {
    int e = blockIdx.x * 256 + threadIdx.x;
    if (e < E0) {
        int m32 = (*flag != 0);
        int d = load_edge(ei, (long long)E0 + e, m32);
        if (d >= 0 && d < NN) atomicAdd(&counts[d], 1);
    }
}

// shfl-based block scan: 1024 threads x 10 values, 2 barriers total.
__global__ __launch_bounds__(1024) void scan_kernel(const int* counts, int* offsets, int* cursor) {
    __shared__ int wsum[16];
    int t = threadIdx.x;
    int lane = t & 63, wv = t >> 6;
    int base = t * 10;
    int local[10];
    int s = 0;
    #pragma unroll
    for (int j = 0; j < 10; ++j) {
        int idx = base + j;
        int v = (idx < NN) ? (counts[idx] + 1) : 0;  // +1 self loop
        local[j] = v; s += v;
    }
    int v = s;
    #pragma unroll
    for (int d = 1; d < 64; d <<= 1) {
        int o = __shfl_up(v, d, 64);
        if (lane >= d) v += o;
    }
    if (lane == 63) wsum[wv] = v;
    __syncthreads();
    if (t < 16) {
        int w = wsum[t];
        #pragma unroll
        for (int d = 1; d < 16; d <<= 1) {
            int o = __shfl_up(w, d, 16);
            if (t >= d) w += o;
        }
        wsum[t] = w;
    }
    __syncthreads();
    int woff = (wv == 0) ? 0 : wsum[wv - 1];
    int run = woff + v - s;
    #pragma unroll
    for (int j = 0; j < 10; ++j) {
        int idx = base + j;
        if (idx < NN) { offsets[idx] = run; cursor[idx] = run; run += local[j]; }
    }
    if (t == 1023) offsets[NN] = wsum[15];
}

__global__ void scatter_kernel(const void* ei, const int* flag, int* cursor, int* csr_src) {
    int e = blockIdx.x * 256 + threadIdx.x;
    if (e >= ETOT) return;
    int m32 = (*flag != 0);
    int s, d;
    if (e < E0) { s = load_edge(ei, e, m32); d = load_edge(ei, (long long)E0 + e, m32); }
    else { s = d = e - E0; }
    if (s < 0) s = 0; if (s >= NN) s = NN - 1;
    if (d < 0) d = 0; if (d >= NN) d = NN - 1;
    int pos = atomicAdd(&cursor[d], 1);
    if (pos >= 0 && pos < ETOT) csr_src[pos] = s;
}

// ---------------- fused fp32->bf16 conversions (x, W1^T, W2^T in one launch) ----------------
__global__ void convall_kernel(const void* x, const void* W1, const void* W2,
                               unsigned short* xb, unsigned short* W1t, unsigned short* W2t,
                               const int* isf32)
{
    int i = blockIdx.x * 256 + threadIdx.x;
    int f = *isf32;
    if (i < NX) { xb[i] = f2bf(loadf(x, i, f)); return; }
    i -= NX;
    if (i < NW1) {
        int r = i / HID1, c = i % HID1;
        W1t[(size_t)c * IN_DIM + r] = f2bf(loadf(W1, i, f));
        return;
    }
    i -= NW1;
    if (i < NW2) {
        int r = i / EMB, c = i % EMB;
        W2t[(size_t)c * HID1 + r] = f2bf(loadf(W2, i, f));
    }
}

// ---------------- m97-style MFMA GEMM with fused alpha epilogue ----------------
// C[Mpad,N] = A[Mpad,K] * Bt[N,K]^T, bf16 out; additionally accumulates
// as_out[row*HN + head] += sum_c C[row][c]*a_src[c] (head = col>>HSHIFT) via
// shfl-reduced partials + one guarded f32 atomicAdd per (row, colblock) —
// low-contention (<=8 adders/slot) and co-resident with GEMM compute.
template<int HSHIFT, int HN>
__global__ __launch_bounds__(256) void gemm_tile(
    const unsigned short* __restrict__ A,
    const unsigned short* __restrict__ Bt,
    void* __restrict__ Cv, int N, int K,
    const void* __restrict__ a_src, const void* __restrict__ a_dst,
    const int* __restrict__ isf32,
    float* __restrict__ as_out, float* __restrict__ ad_out)
{
    __shared__ unsigned short As[128 * 32];
    __shared__ unsigned short Bs[128 * 32];
    int t = threadIdx.x;
    int wave = t >> 6;
    int lane = t & 63;
    int quad = lane >> 4;
    int l16  = lane & 15;
    int mq = wave & 1, nq = wave >> 1;
    size_t mblk = (size_t)blockIdx.x * 128;
    size_t nblk = (size_t)blockIdx.y * 128;

    floatx4 acc[4][4];
    #pragma unroll
    for (int i = 0; i < 4; ++i)
        #pragma unroll
        for (int j = 0; j < 4; ++j)
            acc[i][j] = (floatx4){0.f, 0.f, 0.f, 0.f};

    const unsigned short* Abase = A + mblk * K;
    const unsigned short* Bbase = Bt + nblk * K;

    for (int kk = 0; kk < K; kk += 32) {
        __syncthreads();
        #pragma unroll
        for (int j = 0; j < 2; ++j) {
            int chunk = (wave << 7) + (j << 6) + lane;
            int r  = chunk >> 2;
            int cs = (chunk & 3) ^ (r & 3);
            const unsigned short* ga = Abase + (size_t)r * K + kk + cs * 8;
            const unsigned short* gb = Bbase + (size_t)r * K + kk + cs * 8;
            __builtin_amdgcn_global_load_lds(
                (const __attribute__((address_space(1))) void*)ga,
                (__attribute__((address_space(3))) void*)(As + (size_t)((wave << 7) + (j << 6)) * 8),
                16, 0, 0);
            __builtin_amdgcn_global_load_lds(
                (const __attribute__((address_space(1))) void*)gb,
                (__attribute__((address_space(3))) void*)(Bs + (size_t)((wave << 7) + (j << 6)) * 8),
                16, 0, 0);
        }
        __syncthreads();

        short8 af[4], bf[4];
        #pragma unroll
        for (int i = 0; i < 4; ++i) {
            int ar = mq * 64 + i * 16 + l16;
            int br = nq * 64 + i * 16 + l16;
            af[i] = *(const short8*)(const void*)(As + ar * 32 + (quad ^ (ar & 3)) * 8);
            bf[i] = *(const short8*)(const void*)(Bs + br * 32 + (quad ^ (br & 3)) * 8);
        }
        #pragma unroll
        for (int i = 0; i < 4; ++i)
            #pragma unroll
            for (int j = 0; j < 4; ++j)
                acc[i][j] = __builtin_amdgcn_mfma_f32_16x16x32_bf16(af[i], bf[j], acc[i][j], 0, 0, 0);
    }

    size_t crow0 = mblk + mq * 64 + quad * 4;
    size_t ccol0 = nblk + nq * 64 + l16;
    #pragma unroll
    for (int i = 0; i < 4; ++i) {
        #pragma unroll
        for (int r = 0; r < 4; ++r) {
            size_t row = crow0 + i * 16 + r;
            size_t b = row * N + ccol0;
            #pragma unroll
            for (int j = 0; j < 4; ++j)
                ((unsigned short*)Cv)[b + j * 16] = f2bf(acc[i][j][r]);
        }
    }

    // fused alpha partials (uses pre-rounding f32 acc — closer to ref than bf16 h)
    int f = *isf32;
    float a_s[4], a_d[4];
    #pragma unroll
    for (int j = 0; j < 4; ++j) {
        a_s[j] = loadf(a_src, ccol0 + j * 16, f);
        a_d[j] = loadf(a_dst, ccol0 + j * 16, f);
    }
    int head = (int)((nblk + (size_t)nq * 64) >> HSHIFT);
    #pragma unroll
    for (int i = 0; i < 4; ++i) {
        #pragma unroll
        for (int r = 0; r < 4; ++r) {
            float ps = acc[i][0][r] * a_s[0] + acc[i][1][r] * a_s[1]
                     + acc[i][2][r] * a_s[2] + acc[i][3][r] * a_s[3];
            float pd = acc[i][0][r] * a_d[0] + acc[i][1][r] * a_d[1]
                     + acc[i][2][r] * a_d[2] + acc[i][3][r] * a_d[3];
            #pragma unroll
            for (int off = 1; off < 16; off <<= 1) {
                ps += __shfl_xor(ps, off, 16);
                pd += __shfl_xor(pd, off, 16);
            }
            if (l16 == 0) {
                size_t row = crow0 + i * 16 + r;
                if (row < NN) {
                    atomicAdd(&as_out[row * HN + head], ps);
                    atomicAdd(&ad_out[row * HN + head], pd);
                }
            }
        }
    }
}

// ---------------- layer-1 single-pass softmax-aggregate + ELU -> hmid bf16 ----------------
// R3's proven 49.7us structure: 2 groups x 128 threads, 8 cols/thread, 4-deep edge pipeline.
__global__ __launch_bounds__(256) void agg1_kernel(
    const unsigned short* __restrict__ h1, const int* __restrict__ offsets,
    const int* __restrict__ csr_src, const float* __restrict__ as1,
    const float* __restrict__ ad1, const void* __restrict__ b1,
    const int* __restrict__ isf32,
    unsigned short* __restrict__ hmid)
{
    int n = blockIdx.x, t = threadIdx.x;
    int f = *isf32;
    int beg = offsets[n], end = offsets[n + 1];
    if (beg < 0) beg = 0; if (end > ETOT) end = ETOT;
    int g = t >> 7;          // edge group 0/1
    int u = t & 127;
    int c0 = u * 8;          // 8 cols per thread
    int hc = u >> 4;         // head = c0/128
    float ad = ad1[n * 8 + hc];

    float den = 0.f;
    float acc[8];
    #pragma unroll
    for (int j = 0; j < 8; ++j) acc[j] = 0.f;

    int i = beg + g;
    for (; i + 6 < end; i += 8) {
        int s0 = csr_src[i];     s0 &= 0x7fffffff; if (s0 >= NN) s0 = 0;
        int s1 = csr_src[i + 2]; s1 &= 0x7fffffff; if (s1 >= NN) s1 = 0;
        int s2 = csr_src[i + 4]; s2 &= 0x7fffffff; if (s2 >= NN) s2 = 0;
        int s3 = csr_src[i + 6]; s3 &= 0x7fffffff; if (s3 >= NN) s3 = 0;
        ushort8v hv0 = *(const ushort8v*)(const void*)(h1 + (size_t)s0 * HID1 + c0);
        ushort8v hv1 = *(const ushort8v*)(const void*)(h1 + (size_t)s1 * HID1 + c0);
        ushort8v hv2 = *(const ushort8v*)(const void*)(h1 + (size_t)s2 * HID1 + c0);
        ushort8v hv3 = *(const ushort8v*)(const void*)(h1 + (size_t)s3 * HID1 + c0);
        float e0 = as1[s0 * 8 + hc] + ad;
        float e1 = as1[s1 * 8 + hc] + ad;
        float e2 = as1[s2 * 8 + hc] + ad;
        float e3 = as1[s3 * 8 + hc] + ad;
        e0 = e0 > 0.f ? e0 : 0.2f * e0;
        e1 = e1 > 0.f ? e1 : 0.2f * e1;
        e2 = e2 > 0.f ? e2 : 0.2f * e2;
        e3 = e3 > 0.f ? e3 : 0.2f * e3;
        float w0 = __expf(e0), w1 = __expf(e1), w2 = __expf(e2), w3 = __expf(e3);
        den += (w0 + w1) + (w2 + w3);
        #pragma unroll
        for (int j = 0; j < 8; ++j)
            acc[j] += (bf2f(hv0[j]) * w0 + bf2f(hv1[j]) * w1)
                    + (bf2f(hv2[j]) * w2 + bf2f(hv3[j]) * w3);
    }
    for (; i + 2 < end; i += 4) {
        int s0 = csr_src[i];     s0 &= 0x7fffffff; if (s0 >= NN) s0 = 0;
        int s1 = csr_src[i + 2]; s1 &= 0x7fffffff; if (s1 >= NN) s1 = 0;
        ushort8v hv0 = *(const ushort8v*)(const void*)(h1 + (size_t)s0 * HID1 + c0);
        ushort8v hv1 = *(const ushort8v*)(const void*)(h1 + (size_t)s1 * HID1 + c0);
        float e0 = as1[s0 * 8 + hc] + ad;
        float e1 = as1[s1 * 8 + hc] + ad;
        e0 = e0 > 0.f ? e0 : 0.2f * e0;
        e1 = e1 > 0.f ? e1 : 0.2f * e1;
        float w0 = __expf(e0), w1 = __expf(e1);
        den += w0 + w1;
        #pragma unroll
        for (int j = 0; j < 8; ++j)
            acc[j] += bf2f(hv0[j]) * w0 + bf2f(hv1[j]) * w1;
    }
    if (i < end) {
        int s0 = csr_src[i]; s0 &= 0x7fffffff; if (s0 >= NN) s0 = 0;
        ushort8v hv0 = *(const ushort8v*)(const void*)(h1 + (size_t)s0 * HID1 + c0);
        float e0 = as1[s0 * 8 + hc] + ad;
        e0 = e0 > 0.f ? e0 : 0.2f * e0;
        float w0 = __expf(e0);
        den += w0;
        #pragma unroll
        for (int j = 0; j < 8; ++j) acc[j] += bf2f(hv0[j]) * w0;
    }

    __shared__ float accsh[128][9];
    __shared__ float densh[128];
    if (g == 1) {
        #pragma unroll
        for (int j = 0; j < 8; ++j) accsh[u][j] = acc[j];
        densh[u] = den;
    }
    __syncthreads();
    if (g == 0) {
        den += densh[u];
        float rden = 1.0f / fmaxf(den, 1e-30f);
        ushort8v outw;
        #pragma unroll
        for (int j = 0; j < 8; ++j) {
            float v = (acc[j] + accsh[u][j]) * rden + loadf(b1, c0 + j, f);
            v = v > 0.f ? v : (__expf(v) - 1.0f);   // ELU
            outw[j] = f2bf(v);
        }
        *(ushort8v*)(void*)(hmid + (size_t)n * HID1 + c0) = outw;
    }
}

// ---------------- layer-2 softmax-aggregate, COLUMN-CHUNK-PARTITIONED (R6, ~6us faster) ----------------
__global__ __launch_bounds__(256) void agg2_kernel(
    const unsigned short* __restrict__ h2, const int* __restrict__ offsets,
    const int* __restrict__ csr_src, const float* __restrict__ as2,
    const float* __restrict__ ad2, const void* __restrict__ b2,
    const int* __restrict__ isf32,
    float* __restrict__ out)
{
    int chunk = blockIdx.x & 3;
    int ng    = blockIdx.x >> 2;
    int n     = ng * 4 + (threadIdx.x >> 6);
    if (n >= NN) return;
    int lane = threadIdx.x & 63;
    int q    = lane >> 4;      // edge quarter-group 0..3
    int sl   = lane & 15;      // 4 cols: chunk*64 + sl*4 ..
    int f = *isf32;
    int beg = offsets[n], end = offsets[n + 1];
    if (beg < 0) beg = 0; if (end > ETOT) end = ETOT;
    float adn = ad2[n];
    const unsigned* rb = (const unsigned*)h2 + chunk * 32 + sl * 2;  // + s*128 (u32 units)

    float den = 0.f;
    float acc[4];
    #pragma unroll
    for (int j = 0; j < 4; ++j) acc[j] = 0.f;

    int i = beg + q;
    for (; i + 12 < end; i += 16) {
        int s0 = csr_src[i];      s0 &= 0x7fffffff; if (s0 >= NN) s0 = 0;
        int s1 = csr_src[i + 4];  s1 &= 0x7fffffff; if (s1 >= NN) s1 = 0;
        int s2 = csr_src[i + 8];  s2 &= 0x7fffffff; if (s2 >= NN) s2 = 0;
        int s3 = csr_src[i + 12]; s3 &= 0x7fffffff; if (s3 >= NN) s3 = 0;
        uint2v v0 = *(const uint2v*)(const void*)(rb + (size_t)s0 * 128);
        uint2v v1 = *(const uint2v*)(const void*)(rb + (size_t)s1 * 128);
        uint2v v2 = *(const uint2v*)(const void*)(rb + (size_t)s2 * 128);
        uint2v v3 = *(const uint2v*)(const void*)(rb + (size_t)s3 * 128);
        float w0 = __expf(lrelu(as2[s0] + adn));
        float w1 = __expf(lrelu(as2[s1] + adn));
        float w2 = __expf(lrelu(as2[s2] + adn));
        float w3 = __expf(lrelu(as2[s3] + adn));
        den += (w0 + w1) + (w2 + w3);
        acc[0] += (bflo(v0[0]) * w0 + bflo(v1[0]) * w1) + (bflo(v2[0]) * w2 + bflo(v3[0]) * w3);
        acc[1] += (bfhi(v0[0]) * w0 + bfhi(v1[0]) * w1) + (bfhi(v2[0]) * w2 + bfhi(v3[0]) * w3);
        acc[2] += (bflo(v0[1]) * w0 + bflo(v1[1]) * w1) + (bflo(v2[1]) * w2 + bflo(v3[1]) * w3);
        acc[3] += (bfhi(v0[1]) * w0 + bfhi(v1[1]) * w1) + (bfhi(v2[1]) * w2 + bfhi(v3[1]) * w3);
    }
    for (; i + 4 < end; i += 8) {
        int s0 = csr_src[i];     s0 &= 0x7fffffff; if (s0 >= NN) s0 = 0;
        int s1 = csr_src[i + 4]; s1 &= 0x7fffffff; if (s1 >= NN) s1 = 0;
        uint2v v0 = *(const uint2v*)(const void*)(rb + (size_t)s0 * 128);
        uint2v v1 = *(const uint2v*)(const void*)(rb + (size_t)s1 * 128);
        float w0 = __expf(lrelu(as2[s0] + adn));
        float w1 = __expf(lrelu(as2[s1] + adn));
        den += w0 + w1;
        acc[0] += bflo(v0[0]) * w0 + bflo(v1[0]) * w1;
        acc[1] += bfhi(v0[0]) * w0 + bfhi(v1[0]) * w1;
        acc[2] += bflo(v0[1]) * w0 + bflo(v1[1]) * w1;
        acc[3] += bfhi(v0[1]) * w0 + bfhi(v1[1]) * w1;
    }
    if (i < end) {
        int s0 = csr_src[i]; s0 &= 0x7fffffff; if (s0 >= NN) s0 = 0;
        uint2v v0 = *(const uint2v*)(const void*)(rb + (size_t)s0 * 128);
        float w0 = __expf(lrelu(as2[s0] + adn));
        den += w0;
        acc[0] += bflo(v0[0]) * w0;
        acc[1] += bfhi(v0[0]) * w0;
        acc[2] += bflo(v0[1]) * w0;
        acc[3] += bfhi(v0[1]) * w0;
    }

    #pragma unroll
    for (int j = 0; j < 4; ++j) {
        acc[j] += __shfl_xor(acc[j], 16, 64);
        acc[j] += __shfl_xor(acc[j], 32, 64);
    }
    den += __shfl_xor(den, 16, 64);
    den += __shfl_xor(den, 32, 64);

    if (q == 0) {
        float rden = 1.0f / fmaxf(den, 1e-30f);
        int c0 = chunk * 64 + sl * 4;
        floatx4 o;
        #pragma unroll
        for (int j = 0; j < 4; ++j)
            o[j] = acc[j] * rden + loadf(b2, c0 + j, f);
        *(floatx4*)(void*)(out + (size_t)n * EMB + c0) = o;
    }
}

extern "C" void kernel_launch(void* const* d_in, const int* in_sizes, int n_in,
                              void* d_out, int out_size, void* d_ws, size_t ws_size,
                              hipStream_t stream)
{
    const void* x      = d_in[0];
    const void* edge   = d_in[1];
    const void* W1     = d_in[2];
    const void* a_src1 = d_in[3];
    const void* a_dst1 = d_in[4];
    const void* b1     = d_in[5];
    const void* W2     = d_in[6];
    const void* a_src2 = d_in[7];
    const void* a_dst2 = d_in[8];
    const void* b2     = d_in[9];
    float* out = (float*)d_out;

    char* ws = (char*)d_ws;
    size_t off = 0;
    auto alloc = [&](size_t bytes) -> void* {
        void* p = ws + off;
        off += (bytes + 255) & ~(size_t)255;
        return p;
    };
    // zero span: counts..ad2 contiguous (zeroed by probezero_kernel)
    int*            counts = (int*)alloc((size_t)NN * 4);
    float*          as1    = (float*)alloc((size_t)NN * 8 * 4);
    float*          ad1    = (float*)alloc((size_t)NN * 8 * 4);
    float*          as2    = (float*)alloc((size_t)NN * 4);
    float*          ad2    = (float*)alloc((size_t)NN * 4);
    int             zn     = (int)(((char*)ad2 - (char*)counts) / 4) + NN;
    int*            flags  = (int*)alloc(2 * 4);          // [0]=eflag [1]=isf32 (NOT zeroed)
    int*            offs   = (int*)alloc((NN + 1) * 4);
    int*            cursor = (int*)alloc(NN * 4);
    int*            csr    = (int*)alloc((size_t)ETOT * 4);
    unsigned short* xb     = (unsigned short*)alloc((size_t)MPAD * IN_DIM * 2);
    unsigned short* W1t    = (unsigned short*)alloc((size_t)IN_DIM * HID1 * 2);
    unsigned short* W2t    = (unsigned short*)alloc((size_t)HID1 * EMB * 2);
    unsigned short* h1b    = (unsigned short*)alloc((size_t)MPAD * HID1 * 2);
    unsigned short* hmid   = (unsigned short*)alloc((size_t)MPAD * HID1 * 2);
    unsigned short* h2b    = (unsigned short*)alloc((size_t)MPAD * EMB * 2);
    int* eflag = flags;
    int* isf32 = flags + 1;

    probezero_kernel<<<(zn + 255) / 256, 256, 0, stream>>>(
        (const int*)edge, (const unsigned*)x, counts, zn, eflag, isf32);

    count_kernel<<<(E0 + 255) / 256, 256, 0, stream>>>(edge, eflag, counts);
    scan_kernel<<<1, 1024, 0, stream>>>(counts, offs, cursor);
    scatter_kernel<<<(ETOT + 255) / 256, 256, 0, stream>>>(edge, eflag, cursor, csr);

    convall_kernel<<<(NX + NW1 + NW2 + 255) / 256, 256, 0, stream>>>(
        x, W1, W2, xb, W1t, W2t, isf32);

    // layer 1 GEMM + fused alpha1: h1b = x @ W1; as1/ad1 accumulated in epilogue
    dim3 g1(MPAD / 128, HID1 / 128);
    gemm_tile<7, 8><<<g1, 256, 0, stream>>>(xb, W1t, h1b, HID1, IN_DIM,
                                            a_src1, a_dst1, isf32, as1, ad1);

    agg1_kernel<<<NN, 256, 0, stream>>>(h1b, offs, csr, as1, ad1, b1, isf32, hmid);

    // layer 2 GEMM + fused alpha2: h2b = hmid @ W2; as2/ad2 accumulated in epilogue
    dim3 g2(MPAD / 128, EMB / 128);
    gemm_tile<8, 1><<<g2, 256, 0, stream>>>(hmid, W2t, h2b, EMB, HID1,
                                            a_src2, a_dst2, isf32, as2, ad2);

    // chunk-partitioned agg2: 2500 node-groups x 4 col-chunks
    agg2_kernel<<<(NN / 4) * 4, 256, 0, stream>>>(h2b, offs, csr, as2, ad2, b2, isf32, out);
}